// Round 2
// baseline (1547.467 us; speedup 1.0000x reference)
//
#include <hip/hip_runtime.h>
#include <cstddef>

#define N_PTS 4096
#define DIMK 1024

static constexpr float S_SCALE = 144.26950408889634f;   // 100*log2(e)
static constexpr float TWO_S   = 288.53900817779268f;   // 200*log2(e)
static constexpr float NEG_BIG = -3.4e38f;

// ws layout (floats): [0..4095]=f~2s (shifted)  [4096..8191]=g~2s (shifted)
// Primed/shifted coords: D2 = -2*S*x.y ; f2s_0 = S*(1024 - ||x_i||^2).
// Constant gauge c = 1024*S is self-maintained by the unchanged update code
// and cancels exactly in f2s+g2s-D2 (see round-2 notes).

// ---------------- prep: f~2s init = S*(1024 - ||Xs_i||^2) ----------------
__global__ __launch_bounds__(256) void k_prep(const float* __restrict__ Xs,
                                              float* __restrict__ fvec) {
  int row  = blockIdx.x * 4 + (threadIdx.x >> 6);   // 0..4095
  int lane = threadIdx.x & 63;
  const float* src = Xs + (size_t)row * DIMK;
  float s = 0.f;
#pragma unroll
  for (int r = 0; r < 4; ++r) {
    float4 a = *(const float4*)(src + lane * 4 + r * 256);
    s += a.x * a.x + a.y * a.y + a.z * a.z + a.w * a.w;
  }
#pragma unroll
  for (int off = 32; off; off >>= 1) s += __shfl_xor(s, off);
  if (lane == 0) fvec[row] = (1024.0f - s) * S_SCALE;
}

// ---------------- fp32 tiled GEMM: D2[i][j] = -2*S*dot(Xs_i, Xt_j) ----------------
__global__ __launch_bounds__(256) void k_gemm(const float* __restrict__ A,
                                              const float* __restrict__ B,
                                              float* __restrict__ D) {
  __shared__ float As[16][132];   // pitch 132: write aliasing stays at free 2-way
  __shared__ float Bs[16][132];
  const int t  = threadIdx.x;
  const int tx = t & 15, ty = t >> 4;
  const int row0 = blockIdx.y * 128, col0 = blockIdx.x * 128;
  float acc[8][8];
#pragma unroll
  for (int i = 0; i < 8; ++i)
#pragma unroll
    for (int j = 0; j < 8; ++j) acc[i][j] = 0.f;

  for (int k0 = 0; k0 < DIMK; k0 += 16) {
#pragma unroll
    for (int s2 = 0; s2 < 2; ++s2) {
      int f4i = t + s2 * 256;
      int r   = f4i >> 2;            // 0..127 tile row
      int kp  = (f4i & 3) << 2;      // 0,4,8,12
      float4 a4 = *(const float4*)(A + (size_t)(row0 + r) * DIMK + k0 + kp);
      float4 b4 = *(const float4*)(B + (size_t)(col0 + r) * DIMK + k0 + kp);
      As[kp + 0][r] = a4.x; As[kp + 1][r] = a4.y; As[kp + 2][r] = a4.z; As[kp + 3][r] = a4.w;
      Bs[kp + 0][r] = b4.x; Bs[kp + 1][r] = b4.y; Bs[kp + 2][r] = b4.z; Bs[kp + 3][r] = b4.w;
    }
    __syncthreads();
#pragma unroll
    for (int kk = 0; kk < 16; ++kk) {
      float a[8], b[8];
      *(float4*)(a)     = *(const float4*)(&As[kk][ty * 8]);
      *(float4*)(a + 4) = *(const float4*)(&As[kk][ty * 8 + 4]);
      *(float4*)(b)     = *(const float4*)(&Bs[kk][tx * 8]);
      *(float4*)(b + 4) = *(const float4*)(&Bs[kk][tx * 8 + 4]);
#pragma unroll
      for (int i = 0; i < 8; ++i)
#pragma unroll
        for (int j = 0; j < 8; ++j) acc[i][j] = fmaf(a[i], b[j], acc[i][j]);
    }
    __syncthreads();
  }
#pragma unroll
  for (int i = 0; i < 8; ++i) {
    int row = row0 + ty * 8 + i;
    float* out = D + (size_t)row * N_PTS + col0 + tx * 8;
#pragma unroll
    for (int j4 = 0; j4 < 2; ++j4) {
      float4 o;
      o.x = -TWO_S * acc[i][j4 * 4 + 0];
      o.y = -TWO_S * acc[i][j4 * 4 + 1];
      o.z = -TWO_S * acc[i][j4 * 4 + 2];
      o.w = -TWO_S * acc[i][j4 * 4 + 3];
      *(float4*)(out + j4 * 4) = o;
    }
  }
}

// ---------------- column LSE (g update): g~2s_j = 12 - log2 sum_i 2^(f~2s_i - D2_ij) ----------------
__global__ __launch_bounds__(256) void k_colpass(const float* __restrict__ D,
                                                 const float* __restrict__ fvec,
                                                 float* __restrict__ gvec) {
  __shared__ float fs[N_PTS];
  __shared__ float Ms[256], Ss[256];
  for (int i = threadIdx.x; i < N_PTS; i += 256) fs[i] = fvec[i];
  __syncthreads();
  const int colLocal = threadIdx.x & 15;
  const int phase    = threadIdx.x >> 4;        // 0..15
  const int col      = (blockIdx.x << 4) | colLocal;
  const float* colp  = D + col;
  float M = NEG_BIG, S = 0.f;
  for (int c = 0; c < 16; ++c) {                // 16 chunks of 16 rows/thread
    int i0 = phase + (c << 8);
    float t[16];
#pragma unroll
    for (int q = 0; q < 16; ++q) {
      int ri = i0 + (q << 4);
      t[q] = fs[ri] - colp[(size_t)ri * N_PTS];
    }
    float Mc = t[0];
#pragma unroll
    for (int q = 1; q < 16; ++q) Mc = fmaxf(Mc, t[q]);
    float Mn = fmaxf(M, Mc);
    float s  = S * exp2f(M - Mn);               // 0*exp2(-big)=0 on first chunk
#pragma unroll
    for (int q = 0; q < 16; ++q) s += exp2f(t[q] - Mn);
    M = Mn; S = s;
  }
  Ms[threadIdx.x] = M; Ss[threadIdx.x] = S;
  __syncthreads();
  if (threadIdx.x < 16) {                       // merge 16 phases per column
    float M0 = Ms[threadIdx.x], S0 = Ss[threadIdx.x];
#pragma unroll
    for (int p = 1; p < 16; ++p) {
      float M1 = Ms[(p << 4) + threadIdx.x], S1 = Ss[(p << 4) + threadIdx.x];
      float Mn = fmaxf(M0, M1);
      S0 = S0 * exp2f(M0 - Mn) + S1 * exp2f(M1 - Mn);
      M0 = Mn;
    }
    gvec[(blockIdx.x << 4) + threadIdx.x] = 12.0f - M0 - log2f(S0);
  }
}

// ---------------- row LSE (f update): f~2s_i = 12 - log2 sum_j 2^(g~2s_j - D2_ij) ----------------
__global__ __launch_bounds__(256) void k_rowpass(const float* __restrict__ D,
                                                 const float* __restrict__ gvec,
                                                 float* __restrict__ fvec) {
  const int row = blockIdx.x;
  const int t   = threadIdx.x;
  const float* rp = D + (size_t)row * N_PTS;
  float v[16];
#pragma unroll
  for (int r = 0; r < 4; ++r) {
    float4 d4 = *(const float4*)(rp + t * 4 + r * 1024);
    float4 g4 = *(const float4*)(gvec + t * 4 + r * 1024);
    v[r * 4 + 0] = g4.x - d4.x;
    v[r * 4 + 1] = g4.y - d4.y;
    v[r * 4 + 2] = g4.z - d4.z;
    v[r * 4 + 3] = g4.w - d4.w;
  }
  float M = v[0];
#pragma unroll
  for (int q = 1; q < 16; ++q) M = fmaxf(M, v[q]);
  float S = 0.f;
#pragma unroll
  for (int q = 0; q < 16; ++q) S += exp2f(v[q] - M);
#pragma unroll
  for (int off = 32; off; off >>= 1) {
    float M2 = __shfl_xor(M, off);
    float S2 = __shfl_xor(S, off);
    float Mn = fmaxf(M, M2);
    S = S * exp2f(M - Mn) + S2 * exp2f(M2 - Mn);
    M = Mn;
  }
  __shared__ float Mw[4], Sw[4];
  int wave = t >> 6, lane = t & 63;
  if (lane == 0) { Mw[wave] = M; Sw[wave] = S; }
  __syncthreads();
  if (t == 0) {
    float M0 = Mw[0], S0 = Sw[0];
#pragma unroll
    for (int w = 1; w < 4; ++w) {
      float Mn = fmaxf(M0, Mw[w]);
      S0 = S0 * exp2f(M0 - Mn) + Sw[w] * exp2f(Mw[w] - Mn);
      M0 = Mn;
    }
    fvec[row] = 12.0f - M0 - log2f(S0);
  }
}

// ---------------- final: P = exp2(0.1*(f~2s_i + g~2s_j - D2_ij)), in place ----------------
__global__ __launch_bounds__(256) void k_final(float* __restrict__ D,
                                               const float* __restrict__ fvec,
                                               const float* __restrict__ gvec) {
  size_t idx4 = ((size_t)blockIdx.x * 256 + threadIdx.x) * 4;
  int i = (int)(idx4 >> 12);
  int j = (int)(idx4 & (N_PTS - 1));
  float4 d  = *(float4*)(D + idx4);
  float4 g4 = *(const float4*)(gvec + j);
  float fi  = fvec[i];
  d.x = exp2f(0.1f * (fi + g4.x - d.x));
  d.y = exp2f(0.1f * (fi + g4.y - d.y));
  d.z = exp2f(0.1f * (fi + g4.z - d.z));
  d.w = exp2f(0.1f * (fi + g4.w - d.w));
  *(float4*)(D + idx4) = d;
}

extern "C" void kernel_launch(void* const* d_in, const int* in_sizes, int n_in,
                              void* d_out, int out_size, void* d_ws, size_t ws_size,
                              hipStream_t stream) {
  const float* Xs = (const float*)d_in[0];
  const float* Xt = (const float*)d_in[1];
  float* D    = (float*)d_out;
  float* ws   = (float*)d_ws;
  float* fvec = ws;
  float* gvec = ws + N_PTS;

  k_prep<<<1024, 256, 0, stream>>>(Xs, fvec);
  k_gemm<<<dim3(32, 32), 256, 0, stream>>>(Xs, Xt, D);
  for (int it = 0; it < 30; ++it) {
    k_colpass<<<256, 256, 0, stream>>>(D, fvec, gvec);
    k_rowpass<<<4096, 256, 0, stream>>>(D, gvec, fvec);
  }
  k_final<<<16384, 256, 0, stream>>>(D, fvec, gvec);
}